// Round 8
// baseline (310.998 us; speedup 1.0000x reference)
//
#include <hip/hip_runtime.h>
#include <hip/hip_bf16.h>

typedef _Float16 f16;
typedef f16 f16x2 __attribute__((ext_vector_type(2)));
typedef f16 f16x4 __attribute__((ext_vector_type(4)));
typedef f16 f16x8 __attribute__((ext_vector_type(8)));
typedef float f32x4 __attribute__((ext_vector_type(4)));

#define RES 512
#define HID 128
#define PTS 256      // points per block
#define WS  168      // f16 row stride for W_lds and xa (160 used + 8 pad, rows 16B-aligned)
#define NVS 40       // f16 row stride for nv_sh

// OUTPUT = FLOAT32 (R7: absmax gained full f32 mantissa -> f32 branch active).
// SAMPLING = f32 "variant C": u = fl(fma(T01, cy, fl(T00*cx))) - 0.5f.
//   R7 falsified variant A (np.einsum C-loop) through the working channel;
//   variant C is what every FMA-based ascending-k accumulation (BLAS sgemm,
//   Eigen/XLA-CPU dot_general, np.matmul) produces: acc=fma(a0,b0,0)=fl(a0b0),
//   then acc=fma(a1,b1,acc). Texel selection for high-m features is the only
//   rounding-sensitive part of the whole problem.
//
// MLP: f16 MFMA, A = W (M=128 outs), B = X^T (N=points); lane owns 4 consecutive
// feature cols of one point. Augmented K=160: [x(128)|nv_i(8)|1.0|0x23];
// W row = [w|lnw_i|bias|0]. Bitwise-validated against a pure f32-VALU MLP (R3==R4).

__global__ __launch_bounds__(256, 1)
void gen_kernel(const float* __restrict__ noise,
                const float* __restrict__ coords,
                const float* __restrict__ trans,
                const float* __restrict__ input_vec,
                const float* __restrict__ lw,
                const float* __restrict__ lb,
                const float* __restrict__ lnw,
                const float* __restrict__ tw1,
                const float* __restrict__ tb1,
                const float* __restrict__ tw2,
                const float* __restrict__ tb2,
                float* __restrict__ out)
{
    __shared__ f16 W_lds[HID * WS];     // 43008 B
    __shared__ f16 xa[PTS * WS];        // 86016 B
    __shared__ f16 nv_sh[PTS * NVS];    // 20480 B
    __shared__ float T_sh[128];         // transformations
    __shared__ float tw2_sh[HID];

    const int t    = threadIdx.x;
    const int wave = t >> 6;
    const int lane = t & 63;
    const int quad = lane >> 4;
    const int l15  = lane & 15;
    const int pbase = blockIdx.x * PTS;
    const int pw    = wave * 64;        // wave-private point rows [pw, pw+64)

    // ---------------- init ----------------
    {   // zero W_lds once (covers the always-zero cols 137..167)
        unsigned long long* wz = (unsigned long long*)W_lds;
        #pragma unroll
        for (int i = 0; i < 21; ++i) wz[t + i * 256] = 0ull;
    }
    {   // xa: cols 0..127 = input_vec (f16), col 136 = 1.0 (bias lane), 137..167 = 0
        const int pr = t >> 1, half = t & 1;
        #pragma unroll
        for (int rr = 0; rr < 2; ++rr) {
            const int p = rr * 128 + pr;
            #pragma unroll
            for (int j = 0; j < 8; ++j) {
                const float4 a = ((const float4*)input_vec)[half * 16 + j * 2];
                const float4 b = ((const float4*)input_vec)[half * 16 + j * 2 + 1];
                f16x8 hv;
                hv[0]=(f16)a.x; hv[1]=(f16)a.y; hv[2]=(f16)a.z; hv[3]=(f16)a.w;
                hv[4]=(f16)b.x; hv[5]=(f16)b.y; hv[6]=(f16)b.z; hv[7]=(f16)b.w;
                *(f16x8*)&xa[p * WS + half * 64 + j * 8] = hv;
            }
        }
        if (t < 128) {
            #pragma unroll
            for (int rr = 0; rr < 2; ++rr) {
                const int p = rr * 128 + t;
                xa[p * WS + 136] = (f16)1.0f;
                for (int c = 137; c < WS; ++c) xa[p * WS + c] = (f16)0.0f;
            }
            T_sh[t]   = trans[t];
            tw2_sh[t] = tw2[t];
        }
    }
    __syncthreads();

    // ---------------- bilinear sampling, f32 variant C (FMA ascending-k) ----------
    {
        #pragma clang fp contract(off)
        const int p = t;
        const float cx = coords[(pbase + p) * 2 + 0];
        const float cy = coords[(pbase + p) * 2 + 1];
        #pragma unroll 4
        for (int m = 0; m < 32; ++m) {
            const float T00 = T_sh[m*4+0], T01 = T_sh[m*4+1];
            const float T10 = T_sh[m*4+2], T11 = T_sh[m*4+3];
            const float p0x = T00 * cx;                       // k=0: fl(cx*T00)
            const float p0y = T10 * cx;
            const float ncx = __builtin_fmaf(T01, cy, p0x);   // k=1: fused accumulate
            const float ncy = __builtin_fmaf(T11, cy, p0y);
            const float u = ncx - 0.5f;                       // separate np ufunc
            const float v = ncy - 0.5f;
            const float xf = floorf(u), yf = floorf(v);
            const float xw = u - xf, yw = v - yf;
            // numpy astype(int32) from f32 = cvttss2si: out-of-range -> INT_MIN
            int ix = (xf >= 2147483648.0f || xf < -2147483648.0f) ? (int)(-2147483647 - 1) : (int)xf;
            int iy = (yf >= 2147483648.0f || yf < -2147483648.0f) ? (int)(-2147483647 - 1) : (int)yf;
            const int x0 = ix & (RES - 1);
            const int x1 = (int)(((unsigned)ix + 1u) & (unsigned)(RES - 1));
            const int y0 = iy & (RES - 1);
            const int y1 = (int)(((unsigned)iy + 1u) & (unsigned)(RES - 1));
            const float* pl = noise + m * (RES * RES);
            const float i00 = pl[y0 * RES + x0];
            const float i01 = pl[y0 * RES + x1];
            const float i10 = pl[y1 * RES + x0];
            const float i11 = pl[y1 * RES + x1];
            const float a0 = i00 + (i01 - i00) * xw;          // separate mul/add = np ufuncs
            const float a1 = i10 + (i11 - i10) * xw;
            nv_sh[p * NVS + m] = (f16)(a0 + (a1 - a0) * yw);
        }
    }
    // nv slice 0 -> xa aug cols 128..135 (own row: pw+lane == t)
    {
        const int p = pw + lane;
        *(f16x8*)&xa[p * WS + 128] = *(const f16x8*)&nv_sh[p * NVS + 0];
    }

    // ---------------- 5 MFMA layers: L0..L3 hidden (+noise), L4 = tw1 ----------------
    f32x4 acc[4][8];
    #pragma unroll 1
    for (int L = 0; L < 5; ++L) {
        __syncthreads();   // all waves done reading previous W_lds; xa writes visible
        {   // stage W (f32 global -> f16 LDS), coalesced
            const float* Wsrc = (L < 4) ? (lw + L * HID * HID) : tw1;
            #pragma unroll
            for (int i = 0; i < 16; ++i) {
                const int idx = t + i * 256;                 // 0..4095 float4s
                const float4 w4 = ((const float4*)Wsrc)[idx];
                const int o = idx >> 5, hh = (idx & 31) * 4;
                f16x4 hv;
                hv[0]=(f16)w4.x; hv[1]=(f16)w4.y; hv[2]=(f16)w4.z; hv[3]=(f16)w4.w;
                *(f16x4*)&W_lds[o * WS + hh] = hv;
            }
            {   // lnw slice (or zeros for tw1) into cols 128..135
                const int o = t >> 1, n = (t & 1) * 4;
                f16x4 hv;
                if (L < 4) {
                    const float4 w4 = ((const float4*)(lnw + L * HID * 8))[t];
                    hv[0]=(f16)w4.x; hv[1]=(f16)w4.y; hv[2]=(f16)w4.z; hv[3]=(f16)w4.w;
                } else {
                    hv[0]=(f16)0.f; hv[1]=(f16)0.f; hv[2]=(f16)0.f; hv[3]=(f16)0.f;
                }
                *(f16x4*)&W_lds[o * WS + 128 + n] = hv;
            }
            if (t < HID) {   // bias into col 136
                const float b = (L < 4) ? lb[L * HID + t] : tb1[t];
                W_lds[t * WS + 136] = (f16)b;
            }
        }
        __syncthreads();

        {
            const f32x4 zero4 = {0.f, 0.f, 0.f, 0.f};
            #pragma unroll
            for (int i = 0; i < 4; ++i)
                #pragma unroll
                for (int mt = 0; mt < 8; ++mt) acc[i][mt] = zero4;
        }
        #pragma unroll
        for (int k = 0; k < 5; ++k) {
            const int kc = k * 32 + quad * 8;
            f16x8 xb[4];
            #pragma unroll
            for (int i = 0; i < 4; ++i)   // B-operand: X rows (points), K-contiguous
                xb[i] = *(const f16x8*)&xa[(pw + i * 16 + l15) * WS + kc];
            #pragma unroll
            for (int mt = 0; mt < 8; ++mt) {
                const f16x8 aw = *(const f16x8*)&W_lds[(mt * 16 + l15) * WS + kc]; // A: W rows
                #pragma unroll
                for (int i = 0; i < 4; ++i)
                    acc[i][mt] = __builtin_amdgcn_mfma_f32_16x16x32_f16(aw, xb[i], acc[i][mt], 0, 0, 0);
            }
        }
        // epilogue: leaky-relu + f16 pack; lane holds 4 consecutive feature cols of point p
        #pragma unroll
        for (int i = 0; i < 4; ++i) {
            const int p = pw + i * 16 + l15;
            #pragma unroll
            for (int mt = 0; mt < 8; ++mt) {
                f16x4 hv;
                #pragma unroll
                for (int r = 0; r < 4; ++r) {
                    float v = acc[i][mt][r];
                    v = fmaxf(v, 0.01f * v);   // leaky_relu(0.01)
                    hv[r] = (f16)v;
                }
                *(f16x4*)&xa[p * WS + mt * 16 + quad * 4] = hv;
            }
        }
        if (L < 3) {   // next layer's nv slice into aug cols (own row)
            const int p = pw + lane;
            *(f16x8*)&xa[p * WS + 128] = *(const f16x8*)&nv_sh[p * NVS + (L + 1) * 8];
        }
    }
    __syncthreads();   // epilogue LDS writes visible before head reads

    // ---------------- head: out = tw2 . h + tb2 (no relu), f32 store ----------------
    {
        const int p = t;
        float s = 0.f;
        #pragma unroll
        for (int j = 0; j < 64; ++j) {
            const f16x2 h2 = *(const f16x2*)&xa[p * WS + j * 2];
            s += tw2_sh[j * 2]     * (float)h2[0];
            s += tw2_sh[j * 2 + 1] * (float)h2[1];
        }
        out[pbase + p] = s + tb2[0];
    }
}

extern "C" void kernel_launch(void* const* d_in, const int* in_sizes, int n_in,
                              void* d_out, int out_size, void* d_ws, size_t ws_size,
                              hipStream_t stream) {
    const float* noise  = (const float*)d_in[0];
    const float* coords = (const float*)d_in[1];
    const float* trans  = (const float*)d_in[2];
    const float* ivec   = (const float*)d_in[3];
    const float* lw     = (const float*)d_in[4];
    const float* lb     = (const float*)d_in[5];
    const float* lnw    = (const float*)d_in[6];
    const float* tw1    = (const float*)d_in[7];
    const float* tb1    = (const float*)d_in[8];
    const float* tw2    = (const float*)d_in[9];
    const float* tb2    = (const float*)d_in[10];
    float* o            = (float*)d_out;   // f32 output (reference dtype)

    const int N    = in_sizes[1] / 2;   // coords is [N,2]
    const int grid = N / PTS;           // 1024
    gen_kernel<<<grid, 256, 0, stream>>>(noise, coords, trans, ivec, lw, lb, lnw,
                                         tw1, tb1, tw2, tb2, o);
}

// Round 9
// 263.537 us; speedup vs baseline: 1.1801x; 1.1801x over previous
//
#include <hip/hip_runtime.h>

typedef _Float16 f16;
typedef f16 f16x4 __attribute__((ext_vector_type(4)));
typedef f16 f16x8 __attribute__((ext_vector_type(8)));
typedef float f32x4 __attribute__((ext_vector_type(4)));

#define RES 512
#define PTS 128     // points per block (4 waves x 32 pts)
#define XS  136     // f16 stride, main K=128 region (+8 pad; 272B rows: 16B-aligned, 2-way banks = free)
#define AS  16      // f16 stride, aug region: [nv(8) | bias=1 | zeros(7)]

// v2 structure: K split into main(128) + aug(16-in-32) so LDS fits 2 blocks/CU
// (78.8 KB). W_main/W_aug staged per layer; xa is WAVE-PRIVATE (rows owned by
// the wave that reads them) so only W staging needs barriers. Sampling: 2
// threads per point x 16 features, nv kept in registers, written into xaug
// (same-wave LDS visibility). Aug MFMA uses the same 16x16x32 intrinsic with
// exec-masked B/A reads: quads 0-1 read the 16 aug cols, quads 2-3 feed zeros.
// Sampling math is bit-identical to the R8-verified variant-C chain.

__global__ __launch_bounds__(256, 2)
void gen_kernel(const float* __restrict__ noise,
                const float* __restrict__ coords,
                const float* __restrict__ trans,
                const float* __restrict__ input_vec,
                const float* __restrict__ lw,
                const float* __restrict__ lb,
                const float* __restrict__ lnw,
                const float* __restrict__ tw1,
                const float* __restrict__ tb1,
                const float* __restrict__ tw2,
                const float* __restrict__ tb2,
                float* __restrict__ out)
{
    __shared__ f16 Wm[128 * XS];        // 34816 B
    __shared__ f16 Waug[128 * AS];      //  4096 B
    __shared__ f16 xa[PTS * XS];        // 34816 B
    __shared__ f16 xaug[PTS * AS];      //  4096 B
    __shared__ float T_sh[128];
    __shared__ __align__(16) float tw2_sh[128];

    const int t    = threadIdx.x;
    const int wave = t >> 6;
    const int lane = t & 63;
    const int q    = lane >> 4;
    const int l15  = lane & 15;
    const int pbase = blockIdx.x * PTS;
    const int pw    = wave * 32;        // wave-private point rows [pw, pw+32)
    const int p = t >> 1, h = t & 1;    // sampling: 2 threads per point

    // ---------------- init ----------------
    if (t < 128) {
        T_sh[t]   = trans[t];
        tw2_sh[t] = tw2[t];
        xaug[t * AS + 8] = (f16)1.0f;          // bias lane
        #pragma unroll
        for (int c = 9; c < 16; ++c) { xaug[t * AS + c] = (f16)0.0f; Waug[t * AS + c] = (f16)0.0f; }
    }
    {   // xa rows = input_vec (f16); thread (p,h) fills its point's half-row
        #pragma unroll
        for (int j = 0; j < 8; ++j) {
            const float4 a = ((const float4*)input_vec)[h * 16 + j * 2];
            const float4 b = ((const float4*)input_vec)[h * 16 + j * 2 + 1];
            f16x8 hv;
            hv[0]=(f16)a.x; hv[1]=(f16)a.y; hv[2]=(f16)a.z; hv[3]=(f16)a.w;
            hv[4]=(f16)b.x; hv[5]=(f16)b.y; hv[6]=(f16)b.z; hv[7]=(f16)b.w;
            *(f16x8*)&xa[p * XS + h * 64 + j * 8] = hv;
        }
    }
    const float tb2_0 = tb2[0];
    __syncthreads();   // T_sh ready

    // ---------------- sampling: thread (p,h) does features 16h..16h+15 ----------
    float nvr[16];
    {
        #pragma clang fp contract(off)
        const float cx = coords[(pbase + p) * 2 + 0];
        const float cy = coords[(pbase + p) * 2 + 1];
        #pragma unroll 4
        for (int k = 0; k < 16; ++k) {
            const int m = h * 16 + k;
            const float T00 = T_sh[m*4+0], T01 = T_sh[m*4+1];
            const float T10 = T_sh[m*4+2], T11 = T_sh[m*4+3];
            const float p0x = T00 * cx;                       // k=0: fl(cx*T00)
            const float p0y = T10 * cx;
            const float ncx = __builtin_fmaf(T01, cy, p0x);   // k=1: fused accumulate
            const float ncy = __builtin_fmaf(T11, cy, p0y);
            const float u = ncx - 0.5f;
            const float v = ncy - 0.5f;
            const float xf = floorf(u), yf = floorf(v);
            const float xw = u - xf, yw = v - yf;
            int ix = (xf >= 2147483648.0f || xf < -2147483648.0f) ? (int)(-2147483647 - 1) : (int)xf;
            int iy = (yf >= 2147483648.0f || yf < -2147483648.0f) ? (int)(-2147483647 - 1) : (int)yf;
            const int x0 = ix & (RES - 1);
            const int x1 = (int)(((unsigned)ix + 1u) & (unsigned)(RES - 1));
            const int y0 = iy & (RES - 1);
            const int y1 = (int)(((unsigned)iy + 1u) & (unsigned)(RES - 1));
            const float* pl = noise + m * (RES * RES);
            const float i00 = pl[y0 * RES + x0];
            const float i01 = pl[y0 * RES + x1];
            const float i10 = pl[y1 * RES + x0];
            const float i11 = pl[y1 * RES + x1];
            const float a0 = i00 + (i01 - i00) * xw;
            const float a1 = i10 + (i11 - i10) * xw;
            nvr[k] = a0 + (a1 - a0) * yw;
        }
    }
    if (h == 0) {   // layer-0 nv (features 0..7); same-wave reader -> no barrier
        f16x8 hv;
        #pragma unroll
        for (int j = 0; j < 8; ++j) hv[j] = (f16)nvr[j];
        *(f16x8*)&xaug[p * AS] = hv;
    }

    // ---------------- 5 MFMA layers ----------------
    f32x4 acc[2][8];
    #pragma unroll 1
    for (int L = 0; L < 5; ++L) {
        __syncthreads();   // all waves done reading previous Wm/Waug
        {   // stage W main (f32 -> f16, stride XS)
            const float* Wsrc = (L < 4) ? (lw + L * 16384) : tw1;
            #pragma unroll
            for (int i = 0; i < 16; ++i) {
                const int idx = t + i * 256;             // 0..4095 float4s
                const float4 w4 = ((const float4*)Wsrc)[idx];
                const int row = idx >> 5, c4 = (idx & 31) * 4;
                f16x4 hv;
                hv[0]=(f16)w4.x; hv[1]=(f16)w4.y; hv[2]=(f16)w4.z; hv[3]=(f16)w4.w;
                *(f16x4*)&Wm[row * XS + c4] = hv;
            }
            {   // Waug cols 0..7 = lnw slice (zeros for tw1)
                const int row = t >> 1, cc = (t & 1) * 4;
                f16x4 hv;
                if (L < 4) {
                    const float4 w4 = *(const float4*)(lnw + L * 1024 + row * 8 + cc);
                    hv[0]=(f16)w4.x; hv[1]=(f16)w4.y; hv[2]=(f16)w4.z; hv[3]=(f16)w4.w;
                } else {
                    hv[0]=(f16)0.f; hv[1]=(f16)0.f; hv[2]=(f16)0.f; hv[3]=(f16)0.f;
                }
                *(f16x4*)&Waug[row * AS + cc] = hv;
            }
            if (t < 128)   // Waug col 8 = bias
                Waug[t * AS + 8] = (f16)((L < 4) ? lb[L * 128 + t] : tb1[t]);
        }
        __syncthreads();

        {
            const f32x4 z4 = {0.f, 0.f, 0.f, 0.f};
            #pragma unroll
            for (int i = 0; i < 2; ++i)
                #pragma unroll
                for (int mt = 0; mt < 8; ++mt) acc[i][mt] = z4;
        }
        const int pr0 = (pw + l15) * XS, pr1 = (pw + 16 + l15) * XS;
        #pragma unroll
        for (int c = 0; c < 4; ++c) {   // main K=128
            const int kc = c * 32 + q * 8;
            const f16x8 xb0 = *(const f16x8*)&xa[pr0 + kc];
            const f16x8 xb1 = *(const f16x8*)&xa[pr1 + kc];
            #pragma unroll
            for (int mt = 0; mt < 8; ++mt) {
                const f16x8 aw = *(const f16x8*)&Wm[(mt * 16 + l15) * XS + kc];
                acc[0][mt] = __builtin_amdgcn_mfma_f32_16x16x32_f16(aw, xb0, acc[0][mt], 0, 0, 0);
                acc[1][mt] = __builtin_amdgcn_mfma_f32_16x16x32_f16(aw, xb1, acc[1][mt], 0, 0, 0);
            }
        }
        {   // aug chunk: quads 0-1 read 16 aug cols, quads 2-3 contribute zeros
            f16x8 xb0 = {}, xb1 = {};
            if (q < 2) {
                xb0 = *(const f16x8*)&xaug[(pw + l15) * AS + q * 8];
                xb1 = *(const f16x8*)&xaug[(pw + 16 + l15) * AS + q * 8];
            }
            #pragma unroll
            for (int mt = 0; mt < 8; ++mt) {
                f16x8 aw = {};
                if (q < 2) aw = *(const f16x8*)&Waug[(mt * 16 + l15) * AS + q * 8];
                acc[0][mt] = __builtin_amdgcn_mfma_f32_16x16x32_f16(aw, xb0, acc[0][mt], 0, 0, 0);
                acc[1][mt] = __builtin_amdgcn_mfma_f32_16x16x32_f16(aw, xb1, acc[1][mt], 0, 0, 0);
            }
        }

        if (L < 4) {
            // epilogue: leaky-relu + pack; wave-private xa rows -> no barrier
            #pragma unroll
            for (int i = 0; i < 2; ++i) {
                const int pr = (pw + i * 16 + l15) * XS;
                #pragma unroll
                for (int mt = 0; mt < 8; ++mt) {
                    f16x4 hv;
                    #pragma unroll
                    for (int r = 0; r < 4; ++r) {
                        float v = acc[i][mt][r];
                        v = fmaxf(v, 0.01f * v);
                        hv[r] = (f16)v;
                    }
                    *(f16x4*)&xa[pr + mt * 16 + q * 4] = hv;
                }
            }
            if (L < 3) {   // next layer's nv into xaug (owning thread; same-wave reader)
                const int Ln = L + 1;
                if ((Ln >> 1) == h) {
                    const int kb = (Ln & 1) * 8;
                    f16x8 hv;
                    #pragma unroll
                    for (int j = 0; j < 8; ++j) hv[j] = (f16)nvr[kb + j];
                    *(f16x8*)&xaug[p * AS] = hv;
                }
            }
        } else {
            // head: out = tw2 . lrelu(h) + tb2; butterfly over quads
            #pragma unroll
            for (int i = 0; i < 2; ++i) {
                float s = 0.f;
                #pragma unroll
                for (int mt = 0; mt < 8; ++mt) {
                    const f32x4 w4 = *(const f32x4*)&tw2_sh[mt * 16 + q * 4];
                    #pragma unroll
                    for (int r = 0; r < 4; ++r) {
                        float v = acc[i][mt][r];
                        v = fmaxf(v, 0.01f * v);
                        s += w4[r] * v;
                    }
                }
                s += __shfl_xor(s, 16);
                s += __shfl_xor(s, 32);
                if (q == 0) out[pbase + pw + i * 16 + l15] = s + tb2_0;
            }
        }
    }
}

extern "C" void kernel_launch(void* const* d_in, const int* in_sizes, int n_in,
                              void* d_out, int out_size, void* d_ws, size_t ws_size,
                              hipStream_t stream) {
    const float* noise  = (const float*)d_in[0];
    const float* coords = (const float*)d_in[1];
    const float* trans  = (const float*)d_in[2];
    const float* ivec   = (const float*)d_in[3];
    const float* lw     = (const float*)d_in[4];
    const float* lb     = (const float*)d_in[5];
    const float* lnw    = (const float*)d_in[6];
    const float* tw1    = (const float*)d_in[7];
    const float* tb1    = (const float*)d_in[8];
    const float* tw2    = (const float*)d_in[9];
    const float* tb2    = (const float*)d_in[10];
    float* o            = (float*)d_out;

    const int N    = in_sizes[1] / 2;   // coords is [N,2]
    const int grid = N / PTS;           // 2048
    gen_kernel<<<grid, 256, 0, stream>>>(noise, coords, trans, ivec, lw, lb, lnw,
                                         tw1, tb1, tw2, tb2, o);
}